// Round 4
// baseline (912.506 us; speedup 1.0000x reference)
//
#include <hip/hip_runtime.h>
#include <cstddef>

// DeformLayer on MI355X. Round 4: kill HBM over-fetch in the MFMA GEMMs.
// R3 profile: k_deform_mfma FETCH=580MB (14x ideal), dur ~= fetch/2.1TB/s ->
// memory-refetch-bound from cross-XCD L2 thrash. Fixes:
//  (a) XCD swizzle: b = blockIdx&7 so batch-b blocks share one XCD's L2.
//  (b) x staged to bf16 (xb16) for deform gathers; deform epilogue also emits
//      bf16 y (ybf) for deconv -> per-XCD live set fits 4MB L2.
//  (c) deconv B-pack becomes raw u16 moves (no conversion).

#define B_EPS 1e-5f

typedef __bf16 bf16x8 __attribute__((ext_vector_type(8)));
typedef float f32x4 __attribute__((ext_vector_type(4)));
typedef unsigned short u16;
typedef unsigned int u32;

__device__ __forceinline__ u32 bfr(float f) {          // fp32 -> bf16 bits (RNE)
    u32 u = __float_as_uint(f);
    return (u + 0x7FFFu + ((u >> 16) & 1u)) >> 16;
}
__device__ __forceinline__ float bf2f(u16 u) {
    return __uint_as_float(((u32)u) << 16);
}

__device__ __forceinline__ void load_lds16(const void* g, void* l) {
    __builtin_amdgcn_global_load_lds(
        (const __attribute__((address_space(1))) unsigned int*)g,
        (__attribute__((address_space(3))) unsigned int*)l, 16, 0, 0);
}

// ---------------- tiny prep kernels ----------------
// x fp32 -> xb16 (bf16), 8.4M elems, 4/thread
__global__ __launch_bounds__(256) void k_x2bf(const float* __restrict__ x,
                                              u16* __restrict__ xb) {
    int i = blockIdx.x * 256 + threadIdx.x;      // 8192 blocks
    float4 v = ((const float4*)x)[i];
    union { u16 s[4]; uint2 u; } r;
    r.s[0] = (u16)bfr(v.x); r.s[1] = (u16)bfr(v.y);
    r.s[2] = (u16)bfr(v.z); r.s[3] = (u16)bfr(v.w);
    ((uint2*)xb)[i] = r.u;
}

// w_off[27][256][9] -> wofft[c][co*9+t] (uniform scalar loads in offset conv)
__global__ __launch_bounds__(256) void k_tr_woff(const float* __restrict__ w,
                                                 float* __restrict__ o) {
    int i = blockIdx.x * 256 + threadIdx.x;      // 62208
    int t9 = i % 9; int r = i / 9; int c = r & 255; int co = r >> 8;
    o[c * 243 + co * 9 + t9] = w[i];
}

// w_dcn[o][c][9] -> Wdb[k][cc][o][40] bf16 (frag-ready A tiles)
__global__ __launch_bounds__(256) void k_prep_wdb(const float* __restrict__ w,
                                                  u16* __restrict__ o) {
    int i = blockIdx.x * 256 + threadIdx.x;      // 737280
    int kk = i % 40; int e = i / 40;
    int oc = e & 255; e >>= 8;
    int cc = e & 7; int k = e >> 3;
    float v = (kk < 32) ? w[oc * 2304 + (cc * 32 + kk) * 9 + k] : 0.f;
    o[i] = (u16)bfr(v);
}

// w_up[ci][co][wr][wc] -> Wtb[cls][cc][o][40] bf16, kk = ci_l*4 + tap
__global__ __launch_bounds__(256) void k_prep_wtb(const float* __restrict__ w,
                                                  u16* __restrict__ o) {
    int i = blockIdx.x * 256 + threadIdx.x;      // 1310720
    int kk = i % 40; int e = i / 40;
    int oc = e & 255; e >>= 8;
    int cc = e & 31; int cls = e >> 5;
    float v = 0.f;
    if (kk < 32) {
        int ci = cc * 8 + (kk >> 2), tap = kk & 3;
        int ca = cls >> 1, cb = cls & 1;
        int wr = (tap >> 1) ? (ca ? 0 : 1) : (ca ? 2 : 3);
        int wc = (tap & 1) ? (cb ? 0 : 1) : (cb ? 2 : 3);
        v = w[ci * 4096 + oc * 16 + wr * 4 + wc];
    }
    o[i] = (u16)bfr(v);
}

// folded BN params: bnp = [sc1|bi1|sc2|bi2], 4x256 floats
__global__ __launch_bounds__(256) void k_bn_prep(
    const float* g1, const float* be1, const float* mu1, const float* va1,
    const float* g2, const float* be2, const float* mu2, const float* va2,
    float* bnp) {
    int t = threadIdx.x;
    float s1 = g1[t] * rsqrtf(va1[t] + B_EPS);
    bnp[t] = s1; bnp[256 + t] = be1[t] - mu1[t] * s1;
    float s2 = g2[t] * rsqrtf(va2[t] + B_EPS);
    bnp[512 + t] = s2; bnp[768 + t] = be2[t] - mu2[t] * s2;
}

// om init: om[b][27][4096] = b_off[co]
__global__ __launch_bounds__(256) void k_om_init(const float* __restrict__ b_off,
                                                 float* __restrict__ om) {
    int i = blockIdx.x * 256 + threadIdx.x;      // 884736
    int co = (i >> 12) % 27;
    om[i] = b_off[co];
}

// ---------------- offset conv partial: 8 c-chunks, atomicAdd into om ---------
// blk = b + 8*(chunk + 8*rg): XCD = b (L2 keeps x[b] slab hot)
__global__ __launch_bounds__(256) void k_offset_conv_part(
    const float* __restrict__ x, const float* __restrict__ wofft,
    float* __restrict__ om)
{
    const int t = threadIdx.x;
    const int b = blockIdx.x & 7;
    const int chunk = (blockIdx.x >> 3) & 7;
    const int rg = blockIdx.x >> 6;
    const int h = (rg << 2) + (t >> 6);
    const int w = t & 63;
    const int c0 = chunk << 5;
    const float* xb = x + ((size_t)b << 20);
    float acc[27];
#pragma unroll
    for (int i = 0; i < 27; ++i) acc[i] = 0.f;
    for (int cl = 0; cl < 32; ++cl) {
        const int c = c0 + cl;
        const float* xc = xb + (c << 12);
        float xv[9];
#pragma unroll
        for (int tr = 0; tr < 3; ++tr) {
            int hh = h + tr - 1;
            bool vy = (unsigned)hh < 64u;
#pragma unroll
            for (int tc = 0; tc < 3; ++tc) {
                int ww = w + tc - 1;
                xv[tr * 3 + tc] = (vy && (unsigned)ww < 64u) ? xc[(hh << 6) + ww] : 0.f;
            }
        }
        const float* wc = wofft + c * 243;
#pragma unroll
        for (int co = 0; co < 27; ++co)
#pragma unroll
            for (int k = 0; k < 9; ++k)
                acc[co] = fmaf(xv[k], wc[co * 9 + k], acc[co]);
    }
    float* omb = om + (size_t)b * 110592 + (h << 6) + w;
#pragma unroll
    for (int co = 0; co < 27; ++co)
        atomicAdd(&omb[co << 12], acc[co]);
}

// ---------------- bilinear coeff prep (packed: 4x u16 idx + 4x bf16 wgt) ------
__global__ __launch_bounds__(256) void k_prep_coeff(
    const float* __restrict__ om, uint4* __restrict__ cpk)
{
    int i = blockIdx.x * 256 + threadIdx.x;      // 294912
    int pix = i & 4095;
    int bk = i >> 12;
    int k = bk % 9;
    int b = bk / 9;
    int h = pix >> 6, w = pix & 63;
    const float* omb = om + (size_t)b * 110592;
    float dy = omb[(k << 12) + pix];
    float dx = omb[((9 + k) << 12) + pix];
    float mr = omb[((18 + k) << 12) + pix];
    float m  = 1.f / (1.f + __expf(-mr));
    float py = dy + (float)(k / 3 - 1 + h);
    float px = dx + (float)(k % 3 - 1 + w);
    float y0f = floorf(py), x0f = floorf(px);
    float wy = py - y0f, wx = px - x0f;
    int y0 = (int)y0f, x0 = (int)x0f;
    int y1 = y0 + 1, x1 = x0 + 1;
    float vy0 = ((unsigned)y0 < 64u) ? 1.f : 0.f;
    float vy1 = ((unsigned)y1 < 64u) ? 1.f : 0.f;
    float vx0 = ((unsigned)x0 < 64u) ? 1.f : 0.f;
    float vx1 = ((unsigned)x1 < 64u) ? 1.f : 0.f;
    int cy0 = min(max(y0, 0), 63), cy1 = min(max(y1, 0), 63);
    int cx0 = min(max(x0, 0), 63), cx1 = min(max(x1, 0), 63);
    u32 xw = (u32)((cy0 << 6) + cx0) | ((u32)((cy0 << 6) + cx1) << 16);
    u32 yw = (u32)((cy1 << 6) + cx0) | ((u32)((cy1 << 6) + cx1) << 16);
    float w00 = m * (1.f - wy) * (1.f - wx) * vy0 * vx0;
    float w01 = m * (1.f - wy) * wx         * vy0 * vx1;
    float w10 = m * wy         * (1.f - wx) * vy1 * vx0;
    float w11 = m * wy         * wx         * vy1 * vx1;
    u32 zw = bfr(w00) | (bfr(w01) << 16);
    u32 ww2 = bfr(w10) | (bfr(w11) << 16);
    cpk[i] = make_uint4(xw, yw, zw, ww2);
}

// ---------------- deform conv MFMA GEMM + BN1 + ReLU -> y (+ybf) ------------
// blk = b + 8*row: XCD = b. M=256 o, N=64 px, K chunks of 32 c (9 k outer).
__global__ __launch_bounds__(256) void k_deform_mfma(
    const u16* __restrict__ xb16, const u16* __restrict__ Wdb,
    const uint4* __restrict__ cpk, const float* __restrict__ bnp,
    float* __restrict__ yout, u16* __restrict__ ybf)
{
    __shared__ __align__(16) u16 sA[256 * 40];
    __shared__ __align__(16) u16 sB[64 * 40];
    const int t = threadIdx.x;
    const int b = blockIdx.x & 7;
    const int row = blockIdx.x >> 3;
    const int pix0 = row << 6;
    const int p = t >> 2;        // gather pixel 0..63
    const int g = t & 3;         // c subgroup (8 channels each)
    const u16* xbb = xb16 + ((size_t)b << 20);

    const int lane = t & 63;
    const int wv = t >> 6;
    const int quad = lane >> 4;
    const int ln = lane & 15;

    f32x4 acc[4][4];
#pragma unroll
    for (int i = 0; i < 4; ++i)
#pragma unroll
        for (int j = 0; j < 4; ++j) acc[i][j] = (f32x4)0.f;

    uint4 q = make_uint4(0, 0, 0, 0);
    for (int ch = 0; ch < 72; ++ch) {
        const int k = ch >> 3;
        const int c0 = (ch & 7) << 5;
        if ((ch & 7) == 0)
            q = cpk[(size_t)(b * 9 + k) * 4096 + pix0 + p];
        const int i00 = q.x & 0xFFFF, i01 = q.x >> 16;
        const int i10 = q.y & 0xFFFF, i11 = q.y >> 16;
        const float w00 = __uint_as_float(q.z << 16);
        const float w01 = __uint_as_float(q.z & 0xFFFF0000u);
        const float w10 = __uint_as_float(q.w << 16);
        const float w11 = __uint_as_float(q.w & 0xFFFF0000u);
        u32 pk[4];
#pragma unroll
        for (int j = 0; j < 8; ++j) {
            const u16* xc = xbb + ((size_t)(c0 + g * 8 + j) << 12);
            float v = w00 * bf2f(xc[i00]) + w01 * bf2f(xc[i01])
                    + w10 * bf2f(xc[i10]) + w11 * bf2f(xc[i11]);
            u32 bv = bfr(v);
            if ((j & 1) == 0) pk[j >> 1] = bv; else pk[j >> 1] |= bv << 16;
        }
        __syncthreads();                       // prior frag reads done
        const u16* gA = Wdb + ch * 10240;      // 20480 B tile
#pragma unroll
        for (int i = 0; i < 5; ++i)
            load_lds16(gA + i * 2048 + t * 8, (char*)sA + i * 4096 + t * 16);
        *(uint4*)&sB[p * 40 + g * 8] = *(const uint4*)pk;
        __syncthreads();                       // drains vmcnt incl. lds loads

        bf16x8 af[4], bg[4];
#pragma unroll
        for (int i = 0; i < 4; ++i) {
            af[i] = *(const bf16x8*)&sA[(wv * 64 + i * 16 + ln) * 40 + quad * 8];
            bg[i] = *(const bf16x8*)&sB[(i * 16 + ln) * 40 + quad * 8];
        }
#pragma unroll
        for (int mi = 0; mi < 4; ++mi)
#pragma unroll
            for (int ni = 0; ni < 4; ++ni)
                acc[mi][ni] = __builtin_amdgcn_mfma_f32_16x16x32_bf16(
                    af[mi], bg[ni], acc[mi][ni], 0, 0, 0);
    }
    const float* sc1 = bnp;
    const float* bi1 = bnp + 256;
    float* yb2 = yout + ((size_t)b << 20);
    u16* yf2 = ybf + ((size_t)b << 20);
#pragma unroll
    for (int mi = 0; mi < 4; ++mi) {
#pragma unroll
        for (int r = 0; r < 4; ++r) {
            int o = wv * 64 + mi * 16 + quad * 4 + r;
            float sc = sc1[o], bi = bi1[o];
#pragma unroll
            for (int ni = 0; ni < 4; ++ni) {
                float v = fmaxf(fmaf(acc[mi][ni][r], sc, bi), 0.f);
                size_t idx = ((size_t)o << 12) + pix0 + ni * 16 + ln;
                yb2[idx] = v;
                yf2[idx] = (u16)bfr(v);
            }
        }
    }
}

// ---------------- deconv MFMA GEMM + BN2 + ReLU -> up ----------------
// blk = b + 8*(h0 + 64*cls): XCD = b, h0 inner so one Wtb class slice stays
// L2-live. M=256 o, N=64 px, K = 256ci x 4tap, chunks of 32 (8 ci).
__global__ __launch_bounds__(256) void k_deconv_mfma(
    const u16* __restrict__ ybf, const u16* __restrict__ Wtb,
    const float* __restrict__ bnp, float* __restrict__ up)
{
    __shared__ __align__(16) u16 sA[256 * 40];
    __shared__ __align__(16) u16 sB[64 * 40];
    const int t = threadIdx.x;
    const int b = blockIdx.x & 7;
    const int r9 = blockIdx.x >> 3;
    const int h0 = r9 & 63;
    const int cls = r9 >> 6;
    const int ca = cls >> 1, cb = cls & 1;
    const int DH0 = ca ? 0 : -1, DH1 = ca ? 1 : 0;
    const int DW0 = cb ? 0 : -1, DW1 = cb ? 1 : 0;
    const u16* yb = ybf + ((size_t)b << 20);
    const int p = t >> 2, g = t & 3;

    const int lane = t & 63;
    const int wv = t >> 6;
    const int quad = lane >> 4;
    const int ln = lane & 15;

    f32x4 acc[4][4];
#pragma unroll
    for (int i = 0; i < 4; ++i)
#pragma unroll
        for (int j = 0; j < 4; ++j) acc[i][j] = (f32x4)0.f;

    for (int cc = 0; cc < 32; ++cc) {
        u32 pk[4];
#pragma unroll
        for (int j = 0; j < 8; ++j) {
            int kk = g * 8 + j;
            int ci = (cc << 3) + (kk >> 2);
            int tap = kk & 3;
            int hh = h0 + ((tap >> 1) ? DH1 : DH0);
            int ww = p + ((tap & 1) ? DW1 : DW0);
            u32 bv = ((unsigned)hh < 64u && (unsigned)ww < 64u)
                      ? (u32)yb[((size_t)ci << 12) + (hh << 6) + ww] : 0u;
            if ((j & 1) == 0) pk[j >> 1] = bv; else pk[j >> 1] |= bv << 16;
        }
        __syncthreads();
        const u16* gA = Wtb + (size_t)(cls * 32 + cc) * 10240;
#pragma unroll
        for (int i = 0; i < 5; ++i)
            load_lds16(gA + i * 2048 + t * 8, (char*)sA + i * 4096 + t * 16);
        *(uint4*)&sB[p * 40 + g * 8] = *(const uint4*)pk;
        __syncthreads();

        bf16x8 af[4], bg[4];
#pragma unroll
        for (int i = 0; i < 4; ++i) {
            af[i] = *(const bf16x8*)&sA[(wv * 64 + i * 16 + ln) * 40 + quad * 8];
            bg[i] = *(const bf16x8*)&sB[(i * 16 + ln) * 40 + quad * 8];
        }
#pragma unroll
        for (int mi = 0; mi < 4; ++mi)
#pragma unroll
            for (int ni = 0; ni < 4; ++ni)
                acc[mi][ni] = __builtin_amdgcn_mfma_f32_16x16x32_bf16(
                    af[mi], bg[ni], acc[mi][ni], 0, 0, 0);
    }
    const float* sc2 = bnp + 512;
    const float* bi2 = bnp + 768;
    float* ub = up + ((size_t)b << 22);
    const int pr = (h0 << 1) + ca;
#pragma unroll
    for (int mi = 0; mi < 4; ++mi) {
#pragma unroll
        for (int r = 0; r < 4; ++r) {
            int o = wv * 64 + mi * 16 + quad * 4 + r;
            float sc = sc2[o], bi = bi2[o];
#pragma unroll
            for (int ni = 0; ni < 4; ++ni) {
                int qc = ((ni * 16 + ln) << 1) + cb;
                float v = fmaxf(fmaf(acc[mi][ni][r], sc, bi), 0.f);
                ub[((size_t)o << 14) + (pr << 7) + qc] = v;
            }
        }
    }
}

extern "C" void kernel_launch(void* const* d_in, const int* in_sizes, int n_in,
                              void* d_out, int out_size, void* d_ws, size_t ws_size,
                              hipStream_t stream)
{
    const float* x     = (const float*)d_in[0];
    const float* w_off = (const float*)d_in[1];
    const float* b_off = (const float*)d_in[2];
    const float* w_dcn = (const float*)d_in[3];
    const float* g1    = (const float*)d_in[4];
    const float* be1   = (const float*)d_in[5];
    const float* mu1   = (const float*)d_in[6];
    const float* va1   = (const float*)d_in[7];
    const float* w_up  = (const float*)d_in[8];
    const float* g2    = (const float*)d_in[9];
    const float* be2   = (const float*)d_in[10];
    const float* mu2   = (const float*)d_in[11];
    const float* va2   = (const float*)d_in[12];

    float* yout = (float*)d_out;                 // 8*256*64*64
    float* up   = (float*)d_out + 8388608;       // 8*256*128*128

    char* ws = (char*)d_ws;
    float* om    = (float*)(ws + 0);             //  3,538,944 B
    float* wofft = (float*)(ws + 3538944);       //    248,832 B
    uint4* cpk   = (uint4*)(ws + 3787776);       //  4,718,592 B
    u16*   Wdb   = (u16*)  (ws + 8506368);       //  1,474,560 B
    u16*   Wtb   = (u16*)  (ws + 9980928);       //  2,621,440 B
    float* bnp   = (float*)(ws + 12602368);      //      4,096 B
    u16*   xb16  = (u16*)  (ws + 12606464);      // 16,777,216 B
    u16*   ybf   = (u16*)  (ws + 29383680);      // 16,777,216 B
    // total ws: ~46.2 MB

    k_x2bf      <<<8192, 256, 0, stream>>>(x, xb16);
    k_tr_woff   <<<243,  256, 0, stream>>>(w_off, wofft);
    k_prep_wdb  <<<2880, 256, 0, stream>>>(w_dcn, Wdb);
    k_prep_wtb  <<<5120, 256, 0, stream>>>(w_up, Wtb);
    k_bn_prep   <<<1,    256, 0, stream>>>(g1, be1, mu1, va1, g2, be2, mu2, va2, bnp);
    k_om_init   <<<3456, 256, 0, stream>>>(b_off, om);
    k_offset_conv_part<<<1024, 256, 0, stream>>>(x, wofft, om);
    k_prep_coeff<<<1152, 256, 0, stream>>>(om, cpk);
    k_deform_mfma<<<512, 256, 0, stream>>>(xb16, Wdb, cpk, bnp, yout, ybf);
    k_deconv_mfma<<<2048,256, 0, stream>>>(ybf, Wtb, bnp, up);
}